// Round 1
// baseline (791.680 us; speedup 1.0000x reference)
//
#include <hip/hip_runtime.h>
#include <stdint.h>

#define DIN 256
#define DOUT 64
#define LMAX 50
#define NEG_INF -1e9f

// ---------------------------------------------------------------------------
// Kernel 1: projection  ep[n][j] = sum_k embed[n][k] * W[j][k]
// 64 rows per block (16 rows per wave), W staged transposed in LDS (stride 65
// -> conflict-free for both the staging store and the k-loop read).
// ---------------------------------------------------------------------------
__global__ __launch_bounds__(256) void proj_kernel(
    const float* __restrict__ embed, const float* __restrict__ W,
    float* __restrict__ ep, int N)
{
    __shared__ float wt[DIN * (DOUT + 1)];  // wt[k*65 + j] = W[j][k]

    const int tid = threadIdx.x;

    // Stage W transposed: element e = j*256 + k. Global read coalesced,
    // LDS store bank = (tid + i) % 32 -> 2 lanes/bank (free).
#pragma unroll 8
    for (int i = 0; i < 64; ++i) {
        int e = tid + i * 256;
        int jj = e >> 8;
        int kk = e & 255;
        wt[kk * 65 + jj] = W[e];
    }
    __syncthreads();

    const int j   = tid & 63;
    const int wv  = tid >> 6;
    const int row0 = blockIdx.x * 64 + wv * 16;
    if (row0 >= N) return;

    float acc[16];
#pragma unroll
    for (int i = 0; i < 16; ++i) acc[i] = 0.f;

    const float* eb = embed + (size_t)row0 * DIN;

    for (int k = 0; k < DIN; k += 4) {
        // lanes j=0..63 read wt[k*65+j]: bank (k+j)%32 -> 2/bank, free
        float w0 = wt[(k + 0) * 65 + j];
        float w1 = wt[(k + 1) * 65 + j];
        float w2 = wt[(k + 2) * 65 + j];
        float w3 = wt[(k + 3) * 65 + j];
#pragma unroll
        for (int i = 0; i < 16; ++i) {
            // wave-uniform address -> single broadcast 16B request
            const float4 e4 = *(const float4*)(eb + (size_t)i * DIN + k);
            acc[i] = fmaf(e4.x, w0, acc[i]);
            acc[i] = fmaf(e4.y, w1, acc[i]);
            acc[i] = fmaf(e4.z, w2, acc[i]);
            acc[i] = fmaf(e4.w, w3, acc[i]);
        }
    }

    float* op = ep + (size_t)row0 * DOUT + j;
#pragma unroll
    for (int i = 0; i < 16; ++i) op[(size_t)i * DOUT] = acc[i];
}

// ---------------------------------------------------------------------------
// Kernel 2: per-node GAT attention + aggregation.
// 1 wave per batch node, 4 nodes per 256-thread block.
// Neighbor rows staged in LDS with stride 65 (conflict-free in both phases).
// ---------------------------------------------------------------------------
__global__ __launch_bounds__(256) void agg_kernel(
    const int* __restrict__ neighs, const void* __restrict__ mask,
    const int* __restrict__ dst_idx, const float* __restrict__ ep,
    const float* __restrict__ a_src, const float* __restrict__ a_dst,
    float* __restrict__ out, int B)
{
    __shared__ float feat[4 * LMAX * 65];   // per-wave 50 rows, stride 65
    __shared__ float attnlds[4 * 64];
    __shared__ float asrc_lds[64];

    const int tid  = threadIdx.x;
    const int lane = tid & 63;
    const int wv   = tid >> 6;
    const int b    = blockIdx.x * 4 + wv;
    if (b >= B) return;  // grid exact for B=50000; defensive only

    if (tid < 64) asrc_lds[tid] = a_src[tid];

    // --- mask storage-format detection (deterministic, uniform) ---
    // mask[1][0] (flat element 50) is always True. Byte storage: word 12 has
    // byte2 = 1 -> value >= 65536. Int32 storage: all words are 0/1.
    const unsigned int* mw = (const unsigned int*)mask;
    const bool byteMode = (mw[12] > 1u);

    // --- dst attention: leaky_relu(dot(ep[dst], a_dst)) ---
    const float adst = a_dst[lane];
    const int   di   = dst_idx[b];
    float pd = ep[(size_t)di * DOUT + lane] * adst;
#pragma unroll
    for (int m = 32; m >= 1; m >>= 1) pd += __shfl_xor(pd, m, 64);
    const float dst_attn = pd >= 0.f ? pd : 0.2f * pd;

    // --- per-lane neighbor mask (lane = l) ---
    bool mvalid = false;
    if (lane < LMAX) {
        const int mi = b * LMAX + lane;
        mvalid = byteMode ? (((const uint8_t*)mask)[mi] != 0)
                          : (((const int*)mask)[mi] != 0);
    }

    // --- stage 50 neighbor rows into LDS (lanes = j, coalesced) ---
    float* fw = feat + wv * (LMAX * 65);
#pragma unroll 10
    for (int l = 0; l < LMAX; ++l) {
        int n = neighs[b * LMAX + l];           // broadcast load, L1-hot
        fw[l * 65 + lane] = ep[(size_t)n * DOUT + lane];
    }
    __syncthreads();  // also covers asrc_lds (written by wave 0)

    // --- phase 1: scores, lanes = l ---
    const int lrow = lane < LMAX ? lane : 0;    // clamp to stay in our slice
    const float* fr = fw + lrow * 65;
    float dot = 0.f;
#pragma unroll
    for (int k = 0; k < DOUT; ++k) dot = fmaf(fr[k], asrc_lds[k], dot);
    const float lr = dot >= 0.f ? dot : 0.2f * dot;
    float s = (lane < LMAX && mvalid) ? (dst_attn + lr) : NEG_INF;

    float mx = s;
#pragma unroll
    for (int m = 32; m >= 1; m >>= 1) mx = fmaxf(mx, __shfl_xor(mx, m, 64));
    float e = __expf(s - mx);                   // masked: exp(~-1e9) == 0
    float se = e;
#pragma unroll
    for (int m = 32; m >= 1; m >>= 1) se += __shfl_xor(se, m, 64);
    attnlds[wv * 64 + lane] = e / se;
    __syncthreads();

    // --- phase 2: weighted sum, lanes = j ---
    float acc = 0.f;
#pragma unroll 10
    for (int l = 0; l < LMAX; ++l) {
        acc = fmaf(attnlds[wv * 64 + l], fw[l * 65 + lane], acc);
    }
    out[(size_t)b * DOUT + lane] = acc;
}

// ---------------------------------------------------------------------------
extern "C" void kernel_launch(void* const* d_in, const int* in_sizes, int n_in,
                              void* d_out, int out_size, void* d_ws, size_t ws_size,
                              hipStream_t stream)
{
    const int*   neighs  = (const int*)d_in[0];
    const void*  mask    = d_in[1];
    const int*   dst_idx = (const int*)d_in[2];
    const float* embed   = (const float*)d_in[3];
    const float* W       = (const float*)d_in[4];
    const float* a_src   = (const float*)d_in[5];
    const float* a_dst   = (const float*)d_in[6];
    float* out = (float*)d_out;

    const int B = in_sizes[2];            // 50000
    const int N = in_sizes[3] / DIN;      // 200000

    float* ep = (float*)d_ws;             // N * 64 * 4 = 51.2 MB scratch

    proj_kernel<<<dim3((N + 63) / 64), dim3(256), 0, stream>>>(embed, W, ep, N);
    agg_kernel<<<dim3((B + 3) / 4), dim3(256), 0, stream>>>(
        neighs, mask, dst_idx, ep, a_src, a_dst, out, B);
}